// Round 1
// baseline (79.906 us; speedup 1.0000x reference)
//
#include <hip/hip_runtime.h>
#include <hip/hip_bf16.h>
#include <stdint.h>

// CatLayer: out[i,j,b,c] = sum_k W[c,k] * leaky(concat(x_i, x_j))[k] + bias[c]
// Factorization: leaky commutes with concat =>
//   out[i,j,b,c] = P[i*16+b, c] + Q[j*16+b, c] + bias[c]
//   [P|Q] = leaky(x).reshape(1536,512) @ [W[:, :512]^T | W[:, 512:]^T]  (M=1536,K=512,N=1024)
// GEMM is 1.6 GFLOP (bf16 MFMA); output write (302 MB f32) is the real cost.

typedef __attribute__((ext_vector_type(8))) short short8;
typedef __attribute__((ext_vector_type(4))) float f32x4;

#define L_DIM 96
#define B_DIM 16
#define C_DIM 512
#define M_DIM 1536   // L*B
#define K_DIM 512
#define N_DIM 1024   // 2*C

__device__ inline unsigned short f32_to_bf16(float f) {
    union { float f; uint32_t u; } c; c.f = f;
    uint32_t u = c.u;
    uint32_t r = (u + 0x7FFFu + ((u >> 16) & 1u)) >> 16;  // RNE
    return (unsigned short)r;
}

// ---- prep A: Abf[m][k] = bf16(leaky(x[m*512+k])), 1536x512 ----
__global__ __launch_bounds__(256) void prep_a(const float* __restrict__ x,
                                              unsigned short* __restrict__ Abf) {
    int t = blockIdx.x * 256 + threadIdx.x;            // 98304 threads, 8 elems each
    const f32x4* src = (const f32x4*)x + (size_t)t * 2;
    f32x4 v0 = src[0], v1 = src[1];
    short8 o;
    float vals[8] = {v0.x, v0.y, v0.z, v0.w, v1.x, v1.y, v1.z, v1.w};
#pragma unroll
    for (int e = 0; e < 8; ++e) {
        float f = vals[e];
        f = f > 0.f ? f : 0.1f * f;
        o[e] = (short)f32_to_bf16(f);
    }
    *(short8*)(Abf + (size_t)t * 8) = o;
}

// ---- prep B: Bt[n][k] = bf16( n<512 ? W[n,k] : W[n-512, 512+k] ), 1024x512 ----
__global__ __launch_bounds__(256) void prep_b(const float* __restrict__ W,
                                              unsigned short* __restrict__ Bt) {
    int t = blockIdx.x * 256 + threadIdx.x;            // 65536 threads, 8 elems each
    int n  = t >> 6;
    int kc = (t & 63) << 3;
    const float* src = (n < C_DIM) ? (W + (size_t)n * N_DIM + kc)
                                   : (W + (size_t)(n - C_DIM) * N_DIM + C_DIM + kc);
    const f32x4* s4 = (const f32x4*)src;
    f32x4 v0 = s4[0], v1 = s4[1];
    float vals[8] = {v0.x, v0.y, v0.z, v0.w, v1.x, v1.y, v1.z, v1.w};
    short8 o;
#pragma unroll
    for (int e = 0; e < 8; ++e) o[e] = (short)f32_to_bf16(vals[e]);
    *(short8*)(Bt + (size_t)n * K_DIM + kc) = o;
}

// ---- GEMM: C[m][n] = sum_k A[m][k]*Bt[n][k] (+bias for n<512), 128x128 tile, 4 waves ----
#define LDS_STRIDE 40   // 32 + 8 pad: breaks 8-way bank conflict on frag reads
__global__ __launch_bounds__(256) void gemm_pq(const unsigned short* __restrict__ A,
                                               const unsigned short* __restrict__ Bt,
                                               const float* __restrict__ bias,
                                               float* __restrict__ C) {
    __shared__ unsigned short As[128 * LDS_STRIDE];
    __shared__ unsigned short Bs[128 * LDS_STRIDE];
    const int bm = blockIdx.x;            // 0..11
    const int bn = blockIdx.y;            // 0..7
    const int tid = threadIdx.x;
    const int lane = tid & 63;
    const int w  = tid >> 6;
    const int wr = w >> 1, wc = w & 1;    // wave -> 64x64 quadrant
    const int l15 = lane & 15, l4 = lane >> 4;

    f32x4 acc[4][4] = {};

    for (int kt = 0; kt < K_DIM / 32; ++kt) {
        __syncthreads();
#pragma unroll
        for (int r = 0; r < 2; ++r) {
            int chunk = tid + 256 * r;        // 512 chunks of 16B per tile
            int row = chunk >> 2;
            int kc  = (chunk & 3) << 3;
            short8 va = *(const short8*)(A  + (size_t)(bm * 128 + row) * K_DIM + kt * 32 + kc);
            *(short8*)(&As[row * LDS_STRIDE + kc]) = va;
            short8 vb = *(const short8*)(Bt + (size_t)(bn * 128 + row) * K_DIM + kt * 32 + kc);
            *(short8*)(&Bs[row * LDS_STRIDE + kc]) = vb;
        }
        __syncthreads();
        short8 a[4], b[4];
#pragma unroll
        for (int m = 0; m < 4; ++m)
            a[m] = *(const short8*)(&As[(wr * 64 + m * 16 + l15) * LDS_STRIDE + l4 * 8]);
#pragma unroll
        for (int n = 0; n < 4; ++n)
            b[n] = *(const short8*)(&Bs[(wc * 64 + n * 16 + l15) * LDS_STRIDE + l4 * 8]);
#pragma unroll
        for (int m = 0; m < 4; ++m)
#pragma unroll
            for (int n = 0; n < 4; ++n)
                acc[m][n] = __builtin_amdgcn_mfma_f32_16x16x32_bf16(a[m], b[n], acc[m][n], 0, 0, 0);
    }

#pragma unroll
    for (int m = 0; m < 4; ++m) {
#pragma unroll
        for (int n = 0; n < 4; ++n) {
            int col = bn * 128 + wc * 64 + n * 16 + l15;
            float bv = (col < C_DIM) ? bias[col] : 0.f;
#pragma unroll
            for (int i = 0; i < 4; ++i) {
                int row = bm * 128 + wr * 64 + m * 16 + l4 * 4 + i;
                C[(size_t)row * N_DIM + col] = acc[m][n][i] + bv;
            }
        }
    }
}

// ---- combine: out[((i*96+j)*16+b)*512+c] = P[i*16+b][c] + Q[j*16+b][c] ----
__global__ __launch_bounds__(256) void combine_k(const f32x4* __restrict__ PQ,
                                                 f32x4* __restrict__ out) {
    const uint32_t total = (uint32_t)L_DIM * L_DIM * B_DIM * (C_DIM / 4);  // 18,874,368
    const uint32_t stride = gridDim.x * blockDim.x;
    for (uint32_t idx = blockIdx.x * blockDim.x + threadIdx.x; idx < total; idx += stride) {
        uint32_t c4 = idx & 127u;
        uint32_t r  = idx >> 7;
        uint32_t b  = r & 15u;
        uint32_t ij = r >> 4;
        uint32_t i  = ij / 96u;
        uint32_t j  = ij - i * 96u;
        f32x4 p = PQ[((size_t)(i * 16u + b)) * 256u + c4];
        f32x4 q = PQ[((size_t)(j * 16u + b)) * 256u + 128u + c4];
        out[idx] = p + q;
    }
}

extern "C" void kernel_launch(void* const* d_in, const int* in_sizes, int n_in,
                              void* d_out, int out_size, void* d_ws, size_t ws_size,
                              hipStream_t stream) {
    const float* x    = (const float*)d_in[0];
    const float* W    = (const float*)d_in[1];
    const float* bias = (const float*)d_in[2];
    float* out = (float*)d_out;

    char* ws = (char*)d_ws;
    unsigned short* Abf = (unsigned short*)ws;                       // 1,572,864 B
    unsigned short* Bt  = (unsigned short*)(ws + 1572864);           // 1,048,576 B
    float*          PQ  = (float*)(ws + 2621440);                    // 6,291,456 B (total 8.9 MB)

    prep_a<<<384, 256, 0, stream>>>(x, Abf);
    prep_b<<<256, 256, 0, stream>>>(W, Bt);
    dim3 g(M_DIM / 128, N_DIM / 128);
    gemm_pq<<<g, 256, 0, stream>>>(Abf, Bt, bias, PQ);
    combine_k<<<4096, 256, 0, stream>>>((const f32x4*)PQ, (f32x4*)out);
}

// Round 2
// 77.877 us; speedup vs baseline: 1.0261x; 1.0261x over previous
//
#include <hip/hip_runtime.h>
#include <hip/hip_bf16.h>
#include <stdint.h>

// CatLayer: out[i,j,b,c] = sum_k W[c,k] * leaky(concat(x_i, x_j))[k] + bias[c]
// Factorization: leaky commutes with concat =>
//   out[i,j,b,c] = P[i*16+b, c] + Q[j*16+b, c]   (bias folded into P)
//   [P|Q] = leaky(x).reshape(1536,512) @ [W[:, :512]^T | W[:, 512:]^T]
// Kernel 1: fused convert+GEMM (M=1536,K=512,N=1024) -> PQ f32 in ws.
// Kernel 2: broadcast-add combine, write-bound (302 MB f32 output).

typedef __attribute__((ext_vector_type(8))) short short8;
typedef __attribute__((ext_vector_type(4))) short short4v;
typedef __attribute__((ext_vector_type(4))) float f32x4;

#define L_DIM 96
#define B_DIM 16
#define C_DIM 512
#define M_DIM 1536   // L*B
#define K_DIM 512
#define N_DIM 1024   // 2*C

__device__ inline unsigned short f32_to_bf16(float f) {
    union { float f; uint32_t u; } c; c.f = f;
    uint32_t u = c.u;
    uint32_t r = (u + 0x7FFFu + ((u >> 16) & 1u)) >> 16;  // RNE
    return (unsigned short)r;
}

// ---- fused GEMM: stage f32 x/W -> leaky+bf16 -> LDS -> MFMA ----
// C[m][n] = sum_k leaky(x)[m][k] * Wt[n][k] (+bias for n<512)
#define LDS_STRIDE 40   // 32 + 8 pad
__global__ __launch_bounds__(256) void gemm_pq(const float* __restrict__ x,
                                               const float* __restrict__ W,
                                               const float* __restrict__ bias,
                                               float* __restrict__ C) {
    __shared__ unsigned short As[128 * LDS_STRIDE];
    __shared__ unsigned short Bs[128 * LDS_STRIDE];
    const int bm = blockIdx.x;            // 0..11
    const int bn = blockIdx.y;            // 0..7
    const int tid = threadIdx.x;
    const int lane = tid & 63;
    const int w  = tid >> 6;
    const int wr = w >> 1, wc = w & 1;    // wave -> 64x64 quadrant
    const int l15 = lane & 15, l4 = lane >> 4;

    // block-uniform W base: n<512 -> W[n][k]; n>=512 -> W[n-512][512+k]
    const float* wbase = (bn < 4) ? (W + (size_t)(bn * 128) * N_DIM)
                                  : (W + (size_t)(bn * 128 - C_DIM) * N_DIM + C_DIM);
    const float* xbase = x + (size_t)(bm * 128) * K_DIM;

    f32x4 acc[4][4] = {};

    for (int kt = 0; kt < K_DIM / 32; ++kt) {
        __syncthreads();
        // stage: 128 rows x 32 k per operand = 1024 f32x4 chunks each
#pragma unroll
        for (int r = 0; r < 4; ++r) {
            int chunk = tid + 256 * r;
            int row = chunk >> 3;
            int kc  = (chunk & 7) << 2;
            f32x4 va = *(const f32x4*)(xbase + (size_t)row * K_DIM + kt * 32 + kc);
            short4v sa;
#pragma unroll
            for (int e = 0; e < 4; ++e) {
                float f = va[e];
                f = f > 0.f ? f : 0.1f * f;
                sa[e] = (short)f32_to_bf16(f);
            }
            *(short4v*)(&As[row * LDS_STRIDE + kc]) = sa;
            f32x4 vb = *(const f32x4*)(wbase + (size_t)row * N_DIM + kt * 32 + kc);
            short4v sb;
#pragma unroll
            for (int e = 0; e < 4; ++e) sb[e] = (short)f32_to_bf16(vb[e]);
            *(short4v*)(&Bs[row * LDS_STRIDE + kc]) = sb;
        }
        __syncthreads();
        short8 a[4], b[4];
#pragma unroll
        for (int m = 0; m < 4; ++m)
            a[m] = *(const short8*)(&As[(wr * 64 + m * 16 + l15) * LDS_STRIDE + l4 * 8]);
#pragma unroll
        for (int n = 0; n < 4; ++n)
            b[n] = *(const short8*)(&Bs[(wc * 64 + n * 16 + l15) * LDS_STRIDE + l4 * 8]);
#pragma unroll
        for (int m = 0; m < 4; ++m)
#pragma unroll
            for (int n = 0; n < 4; ++n)
                acc[m][n] = __builtin_amdgcn_mfma_f32_16x16x32_bf16(a[m], b[n], acc[m][n], 0, 0, 0);
    }

#pragma unroll
    for (int m = 0; m < 4; ++m) {
#pragma unroll
        for (int n = 0; n < 4; ++n) {
            int col = bn * 128 + wc * 64 + n * 16 + l15;
            float bv = (col < C_DIM) ? bias[col] : 0.f;
#pragma unroll
            for (int i = 0; i < 4; ++i) {
                int row = bm * 128 + wr * 64 + m * 16 + l4 * 4 + i;
                C[(size_t)row * N_DIM + col] = acc[m][n][i] + bv;
            }
        }
    }
}

// ---- combine: out[((i*96+j)*16+b)*512+c] = P[i*16+b][c] + Q[j*16+b][c] ----
// Each thread fixes (i,b,c4), holds p in register, iterates 48 j values.
__global__ __launch_bounds__(256) void combine_k(const f32x4* __restrict__ PQ,
                                                 f32x4* __restrict__ out) {
    const int jh   = blockIdx.x & 1;               // j-half: 0 or 1
    const int rest = blockIdx.x >> 1;              // 0..767
    const int t    = rest * 256 + threadIdx.x;     // 0..196607
    const uint32_t c4 = t & 127u;                  // 0..127 (512 floats / 4)
    const uint32_t r  = (uint32_t)t >> 7;          // 0..1535
    const uint32_t b  = r & 15u;
    const uint32_t i  = r >> 4;                    // 0..95

    const f32x4 p = PQ[(size_t)r * 256u + c4];     // P[i*16+b][c4]
    const f32x4* qrow = PQ + (size_t)b * 256u + 128u + c4;   // Q[j*16+b], j=0
    f32x4* orow = out + ((size_t)(i * 96u) * 16u + b) * 128u + c4;

    const int j0 = jh * 48, j1 = j0 + 48;
#pragma unroll 4
    for (int j = j0; j < j1; ++j) {
        f32x4 q = qrow[(size_t)j * 16u * 256u];
        __builtin_nontemporal_store(p + q, orow + (size_t)j * 16u * 128u);
    }
}

extern "C" void kernel_launch(void* const* d_in, const int* in_sizes, int n_in,
                              void* d_out, int out_size, void* d_ws, size_t ws_size,
                              hipStream_t stream) {
    const float* x    = (const float*)d_in[0];
    const float* W    = (const float*)d_in[1];
    const float* bias = (const float*)d_in[2];
    float* out = (float*)d_out;

    float* PQ = (float*)d_ws;                      // 1536 x 1024 f32 = 6,291,456 B

    dim3 g(M_DIM / 128, N_DIM / 128);
    gemm_pq<<<g, 256, 0, stream>>>(x, W, bias, PQ);
    combine_k<<<1536, 256, 0, stream>>>((const f32x4*)PQ, (f32x4*)out);
}